// Round 2
// baseline (1176.804 us; speedup 1.0000x reference)
//
#include <hip/hip_runtime.h>
#include <math.h>

#define NB 2
#define NT 2048
#define NDM 1024
#define NH 16
#define NHKV 4
#define NDH 64
#define NLAT 64
#define NDFF 4096

typedef __attribute__((ext_vector_type(4))) float fx4;
typedef __attribute__((ext_vector_type(8))) short bf8;
typedef __attribute__((ext_vector_type(4))) unsigned short us4;

__device__ __forceinline__ unsigned short f2bf(float f) {
  union { float f; unsigned int u; } v; v.f = f;
  unsigned int u = v.u;
  u += 0x7fffu + ((u >> 16) & 1u);   // round-to-nearest-even
  return (unsigned short)(u >> 16);
}

// ---------------------------------------------------------------------------
// Tiled MFMA GEMM: C[M,N] = A[M,K] @ B[K,N]
// A: f32 (ABF16=0) or bf16 (ABF16=1), row-major. B: f32 row-major.
// EPI=0: C f32. EPI=1: C = bf16(silu(acc)).
// Block: 256 thr = 4 waves. Tile 64x64, BK=64. Each wave: 16 rows x 64 cols.
// mfma_f32_16x16x32_bf16 fragment layout:
//   A: lane(16g+m) elem j -> A[m][16*(j>>2) + 4g + (j&3)]
//   B: lane(16g+n) elem j -> B[16*(j>>2) + 4g + (j&3)][n]
//   D: lane(16g+n) reg r  -> D[4g + r][n]           (verified m89)
// ---------------------------------------------------------------------------
template<int ABF16, int EPI>
__global__ __launch_bounds__(256) void gemm_k(const void* __restrict__ Ap,
                                              const float* __restrict__ Bp,
                                              void* __restrict__ Cp,
                                              int M, int N, int K) {
  constexpr int LDK = 68;  // bf16 elems per LDS row (pad 4 -> 136B stride)
  __shared__ unsigned short As[64 * LDK];   // [row m][k]
  __shared__ unsigned short Bs[64 * LDK];   // transposed: [col n][k]
  const int t = threadIdx.x;
  const int m0 = blockIdx.x * 64, n0 = blockIdx.y * 64;
  const int lane = t & 63, w = t >> 6;
  const int m16 = lane & 15, g = lane >> 4;
  const int arow = w * 16 + m16;
  fx4 acc[4] = {{0.f,0.f,0.f,0.f},{0.f,0.f,0.f,0.f},{0.f,0.f,0.f,0.f},{0.f,0.f,0.f,0.f}};

  for (int k0 = 0; k0 < K; k0 += 64) {
    __syncthreads();   // previous iter's fragment reads done before overwrite
#pragma unroll
    for (int i = 0; i < 4; ++i) {
      int id = t * 4 + i;                 // 0..1023
      int row = id >> 4, cg = (id & 15) * 4;
      // A tile: 64 rows x 64 k
      if (ABF16) {
        const unsigned short* A = (const unsigned short*)Ap;
        *(us4*)(As + row * LDK + cg) =
            *(const us4*)(A + (size_t)(m0 + row) * K + k0 + cg);
      } else {
        const float* A = (const float*)Ap;
        fx4 a = *(const fx4*)(A + (size_t)(m0 + row) * K + k0 + cg);
        us4 ab = { f2bf(a[0]), f2bf(a[1]), f2bf(a[2]), f2bf(a[3]) };
        *(us4*)(As + row * LDK + cg) = ab;
      }
      // B tile: 64 k-rows x 64 cols, transposed into Bs[n][k]
      fx4 bv = *(const fx4*)(Bp + (size_t)(k0 + row) * N + n0 + cg);
      Bs[(cg + 0) * LDK + row] = f2bf(bv[0]);
      Bs[(cg + 1) * LDK + row] = f2bf(bv[1]);
      Bs[(cg + 2) * LDK + row] = f2bf(bv[2]);
      Bs[(cg + 3) * LDK + row] = f2bf(bv[3]);
    }
    __syncthreads();
#pragma unroll
    for (int ks = 0; ks < 2; ++ks) {
      const int kb = ks * 32;
      us4 a0 = *(const us4*)(As + arow * LDK + kb + 4 * g);
      us4 a1 = *(const us4*)(As + arow * LDK + kb + 16 + 4 * g);
      bf8 af;
      af[0] = (short)a0[0]; af[1] = (short)a0[1]; af[2] = (short)a0[2]; af[3] = (short)a0[3];
      af[4] = (short)a1[0]; af[5] = (short)a1[1]; af[6] = (short)a1[2]; af[7] = (short)a1[3];
#pragma unroll
      for (int nt = 0; nt < 4; ++nt) {
        const int brow = nt * 16 + m16;
        us4 b0 = *(const us4*)(Bs + brow * LDK + kb + 4 * g);
        us4 b1 = *(const us4*)(Bs + brow * LDK + kb + 16 + 4 * g);
        bf8 bf_;
        bf_[0] = (short)b0[0]; bf_[1] = (short)b0[1]; bf_[2] = (short)b0[2]; bf_[3] = (short)b0[3];
        bf_[4] = (short)b1[0]; bf_[5] = (short)b1[1]; bf_[6] = (short)b1[2]; bf_[7] = (short)b1[3];
        acc[nt] = __builtin_amdgcn_mfma_f32_16x16x32_bf16(af, bf_, acc[nt], 0, 0, 0);
      }
    }
  }
#pragma unroll
  for (int nt = 0; nt < 4; ++nt) {
#pragma unroll
    for (int r = 0; r < 4; ++r) {
      int row = m0 + w * 16 + 4 * g + r;
      int col = n0 + nt * 16 + m16;
      float vv = acc[nt][r];
      if (EPI == 1) {
        float s = vv / (1.f + __expf(-vv));   // silu
        ((unsigned short*)Cp)[(size_t)row * N + col] = f2bf(s);
      } else {
        ((float*)Cp)[(size_t)row * N + col] = vv;
      }
    }
  }
}

// ---------------------------------------------------------------------------
// In-place RoPE over x[(b,t,heads,64)]: pair (i, i+32), i<32.
// ---------------------------------------------------------------------------
__global__ void rope_k(float* __restrict__ x, int nheads, int total) {
  int idx = blockIdx.x * 256 + threadIdx.x;
  if (idx >= total) return;
  int i = idx & 31;
  int rest = idx >> 5;                   // (b*NT + t)*nheads + h
  int tpos = (rest / nheads) % NT;
  float* p = x + (size_t)rest * NDH;
  float ang = (float)tpos * powf(10000.0f, -(float)i * (1.0f / 32.0f));
  float sn, cs;
  sincosf(ang, &sn, &cs);
  float x1 = p[i], x2 = p[i + 32];
  p[i]      = x1 * cs - x2 * sn;
  p[i + 32] = x2 * cs + x1 * sn;
}

// ---------------------------------------------------------------------------
// Flash attention (causal, GQA) + fused sigmoid gate.
// Grid: (NT/64, NB*NH). Block 256 thr. Thread: q-row r = t>>2, dh-quarter qd = t&3.
// 32-key K/V tiles staged in LDS; online softmax; gate GEMM in epilogue.
// ---------------------------------------------------------------------------
__global__ __launch_bounds__(256) void attn_k(const float* __restrict__ qb,
                                              const float* __restrict__ kb,
                                              const float* __restrict__ vb,
                                              const float* __restrict__ Wg,
                                              const float* __restrict__ bg,
                                              float* __restrict__ outp) {
  __shared__ float kv[64 * 68];   // K rows 0..31, V rows 32..63; reused as out tile
  __shared__ float wgs[64 * 68];  // Wgate [d][c]
  const int t = threadIdx.x;
  const int q0 = blockIdx.x * 64;
  const int bh = blockIdx.y;
  const int b = bh >> 4, h = bh & 15, kvh = h >> 2;
#pragma unroll
  for (int i = 0; i < 16; ++i) {
    int id = t + 256 * i;               // 0..4095
    wgs[(id >> 6) * 68 + (id & 63)] = Wg[id];
  }
  const int r = t >> 2, qd = t & 3;
  const int qrow = q0 + r;
  fx4 qreg[4];
  {
    const float* qp = qb + (((size_t)b * NT + qrow) * NH + h) * NDH + qd * 16;
#pragma unroll
    for (int j = 0; j < 4; ++j) qreg[j] = *(const fx4*)(qp + j * 4);
  }
  float mrun = -INFINITY, lsum = 0.f;
  fx4 acc[4] = {{0.f,0.f,0.f,0.f},{0.f,0.f,0.f,0.f},{0.f,0.f,0.f,0.f},{0.f,0.f,0.f,0.f}};

  for (int s0 = 0; s0 < q0 + 64; s0 += 32) {
    __syncthreads();
#pragma unroll
    for (int i = 0; i < 2; ++i) {
      int id = t * 2 + i;               // 0..511 -> 32 rows x 16 float4-groups
      int sr = id >> 4, cg = (id & 15) * 4;
      const size_t kvoff = (((size_t)b * NT + s0 + sr) * NHKV + kvh) * NDH + cg;
      *(fx4*)(kv + sr * 68 + cg)        = *(const fx4*)(kb + kvoff);
      *(fx4*)(kv + (32 + sr) * 68 + cg) = *(const fx4*)(vb + kvoff);
    }
    __syncthreads();
    float sc[32];
#pragma unroll
    for (int s = 0; s < 32; ++s) {
      const float* kr = kv + s * 68 + qd * 16;
      fx4 pp = qreg[0] * *(const fx4*)(kr)
             + qreg[1] * *(const fx4*)(kr + 4)
             + qreg[2] * *(const fx4*)(kr + 8)
             + qreg[3] * *(const fx4*)(kr + 12);
      float p = pp[0] + pp[1] + pp[2] + pp[3];
      p += __shfl_xor(p, 1);
      p += __shfl_xor(p, 2);
      sc[s] = (s0 + s <= qrow) ? p * 0.125f : -INFINITY;
    }
    float tm = sc[0];
#pragma unroll
    for (int s = 1; s < 32; ++s) tm = fmaxf(tm, sc[s]);
    float mnew = fmaxf(mrun, tm);
    float corr = __expf(mrun - mnew);    // first tile: exp(-inf)=0
    lsum *= corr;
#pragma unroll
    for (int j = 0; j < 4; ++j) acc[j] *= corr;
#pragma unroll
    for (int s = 0; s < 32; ++s) {
      float p = __expf(sc[s] - mnew);    // masked -> exp(-inf)=0
      lsum += p;
      const float* vr = kv + (32 + s) * 68 + qd * 16;
      acc[0] += *(const fx4*)(vr)      * p;
      acc[1] += *(const fx4*)(vr + 4)  * p;
      acc[2] += *(const fx4*)(vr + 8)  * p;
      acc[3] += *(const fx4*)(vr + 12) * p;
    }
    mrun = mnew;
  }

  __syncthreads();                       // all PV reads done; reuse kv as out tile
  float inv = 1.0f / lsum;
#pragma unroll
  for (int j = 0; j < 4; ++j) *(fx4*)(kv + r * 68 + qd * 16 + j * 4) = acc[j] * inv;
  __syncthreads();

  // gate: g[c] = sigmoid(bg[c] + sum_d out[r][d] * Wg[d][c]); out *= g
  fx4 gs[4];
#pragma unroll
  for (int j = 0; j < 4; ++j) gs[j] = *(const fx4*)(bg + qd * 16 + j * 4);
  for (int d = 0; d < 64; ++d) {
    float od = kv[r * 68 + d];
    const float* wr = wgs + d * 68 + qd * 16;
#pragma unroll
    for (int j = 0; j < 4; ++j) gs[j] += *(const fx4*)(wr + j * 4) * od;
  }
  float* op = outp + ((size_t)b * NT + qrow) * NDM + h * NDH + qd * 16;
#pragma unroll
  for (int j = 0; j < 4; ++j) {
    fx4 o = *(const fx4*)(kv + r * 68 + qd * 16 + j * 4);
    fx4 res;
#pragma unroll
    for (int e = 0; e < 4; ++e) {
      float gv = 1.f / (1.f + __expf(-gs[j][e]));
      res[e] = o[e] * gv;
    }
    *(fx4*)(op + j * 4) = res;
  }
}

// ---------------------------------------------------------------------------
extern "C" void kernel_launch(void* const* d_in, const int* in_sizes, int n_in,
                              void* d_out, int out_size, void* d_ws, size_t ws_size,
                              hipStream_t stream) {
  const float* x    = (const float*)d_in[0];
  const float* Wq   = (const float*)d_in[1];
  const float* Wkvd = (const float*)d_in[2];
  const float* Wku  = (const float*)d_in[3];
  const float* Wvu  = (const float*)d_in[4];
  const float* Wg   = (const float*)d_in[5];
  const float* bg   = (const float*)d_in[6];
  const float* Wo1  = (const float*)d_in[7];
  const float* Wo2  = (const float*)d_in[8];
  float* out = (float*)d_out;
  char* ws = (char*)d_ws;

  // workspace layout (bytes) — ao aliases d_out (dead before final GEMM writes)
  float* q   = (float*)(ws);                         // 4096*1024 f32 = 16 MB
  float* lat = (float*)(ws + 16777216);              // 4096*64   f32 =  1 MB
  float* kk  = (float*)(ws + 17825792);              // 4096*256  f32 =  4 MB
  float* vv  = (float*)(ws + 22020096);              // 4096*256  f32 =  4 MB
  unsigned short* hbuf = (unsigned short*)(ws + 26214400); // 4096*4096 bf16 = 32 MB
  float* ao  = out;                                  // alias: attn out lives in d_out

  const int MT = NB * NT;  // 4096 token rows
  dim3 blk(256);

  gemm_k<0,0><<<dim3(MT/64, NDM/64),  blk, 0, stream>>>((const void*)x,   Wq,   (void*)q,   MT, NDM,       NDM);
  gemm_k<0,0><<<dim3(MT/64, NLAT/64), blk, 0, stream>>>((const void*)x,   Wkvd, (void*)lat, MT, NLAT,      NDM);
  gemm_k<0,0><<<dim3(MT/64, (NHKV*NDH)/64), blk, 0, stream>>>((const void*)lat, Wku, (void*)kk, MT, NHKV*NDH, NLAT);
  gemm_k<0,0><<<dim3(MT/64, (NHKV*NDH)/64), blk, 0, stream>>>((const void*)lat, Wvu, (void*)vv, MT, NHKV*NDH, NLAT);

  int qpairs = NB * NT * NH * 32;
  int kpairs = NB * NT * NHKV * 32;
  rope_k<<<dim3((qpairs + 255) / 256), blk, 0, stream>>>(q,  NH,   qpairs);
  rope_k<<<dim3((kpairs + 255) / 256), blk, 0, stream>>>(kk, NHKV, kpairs);

  attn_k<<<dim3(NT/64, NB*NH), blk, 0, stream>>>(q, kk, vv, Wg, bg, ao);

  gemm_k<0,1><<<dim3(MT/64, NDFF/64), blk, 0, stream>>>((const void*)ao,   Wo1, (void*)hbuf, MT, NDFF, NDM);
  gemm_k<1,0><<<dim3(MT/64, NDM/64),  blk, 0, stream>>>((const void*)hbuf, Wo2, (void*)out,  MT, NDM,  NDFF);
}

// Round 5
// 533.963 us; speedup vs baseline: 2.2039x; 2.2039x over previous
//
#include <hip/hip_runtime.h>
#include <math.h>

#define NB 2
#define NT 2048
#define NDM 1024
#define NH 16
#define NHKV 4
#define NDH 64
#define NLAT 64
#define NDFF 4096

typedef __attribute__((ext_vector_type(4))) float fx4;
typedef __attribute__((ext_vector_type(8))) short bf8;
typedef __attribute__((ext_vector_type(4))) unsigned short us4;
typedef __attribute__((ext_vector_type(8))) unsigned short us8;

__device__ __forceinline__ unsigned short f2bf(float f) {
  union { float f; unsigned int u; } v; v.f = f;
  unsigned int u = v.u;
  u += 0x7fffu + ((u >> 16) & 1u);   // round-to-nearest-even
  return (unsigned short)(u >> 16);
}

// ---------------------------------------------------------------------------
// f32 -> bf16 elementwise (8 elems/thread)
// ---------------------------------------------------------------------------
__global__ void conv_bf_k(const float* __restrict__ in,
                          unsigned short* __restrict__ out, int n8) {
  int idx = blockIdx.x * 256 + threadIdx.x;
  if (idx >= n8) return;
  fx4 a = *(const fx4*)(in + (size_t)idx * 8);
  fx4 b = *(const fx4*)(in + (size_t)idx * 8 + 4);
  us8 o = { f2bf(a[0]), f2bf(a[1]), f2bf(a[2]), f2bf(a[3]),
            f2bf(b[0]), f2bf(b[1]), f2bf(b[2]), f2bf(b[3]) };
  *(us8*)(out + (size_t)idx * 8) = o;
}

// ---------------------------------------------------------------------------
// Transpose-convert: W[K,N] f32 -> Wt[N,K] bf16. 64x64 tile per block via LDS.
// ---------------------------------------------------------------------------
__global__ __launch_bounds__(256) void convT_bf_k(const float* __restrict__ W,
                                                  unsigned short* __restrict__ Wt,
                                                  int K, int N) {
  __shared__ float tile[64 * 65];
  const int t = threadIdx.x;
  const int k0 = blockIdx.x * 64, n0 = blockIdx.y * 64;
#pragma unroll
  for (int i = 0; i < 4; ++i) {
    int id = t + 256 * i;               // 1024 slots: row=id>>4, c=(id&15)*4
    int row = id >> 4, c = (id & 15) * 4;
    fx4 v = *(const fx4*)(W + (size_t)(k0 + row) * N + n0 + c);
    tile[row * 65 + c + 0] = v[0];
    tile[row * 65 + c + 1] = v[1];
    tile[row * 65 + c + 2] = v[2];
    tile[row * 65 + c + 3] = v[3];
  }
  __syncthreads();
  const int nr = t >> 2, kc = (t & 3) * 16;
  us8 o0, o1;
#pragma unroll
  for (int e = 0; e < 8; ++e) o0[e] = f2bf(tile[(kc + e) * 65 + nr]);
#pragma unroll
  for (int e = 0; e < 8; ++e) o1[e] = f2bf(tile[(kc + 8 + e) * 65 + nr]);
  *(us8*)(Wt + (size_t)(n0 + nr) * K + k0 + kc) = o0;
  *(us8*)(Wt + (size_t)(n0 + nr) * K + k0 + kc + 8) = o1;
}

// ---------------------------------------------------------------------------
// bf16 GEMM, 128x128 tile, BK=64, 4 waves (each owns a 64x64 quadrant).
// A[M,K] bf16 row-major; Bt[N,K] bf16 row-major (pre-transposed weights).
// LDS layout (both tiles): fragment order pos(k)=32*(k>>5)+8*((k&15)>>2)
//   +4*((k>>4)&1)+(k&3), XOR-swizzled by ((row&7)<<3) -> every MFMA operand
//   is one aligned ds_read_b128. EPI=0: f32 C. EPI=1: bf16(silu(C)).
// ---------------------------------------------------------------------------
template<int EPI>
__global__ __launch_bounds__(256) void gemm_bf_k(const unsigned short* __restrict__ A,
                                                 const unsigned short* __restrict__ Bt,
                                                 void* __restrict__ Cp,
                                                 int M, int N, int K) {
  __shared__ unsigned short As[128 * 72];
  __shared__ unsigned short Bs[128 * 72];
  const int t = threadIdx.x;
  const int m0 = blockIdx.x * 128, n0 = blockIdx.y * 128;
  const int lane = t & 63, w = t >> 6;
  const int n = lane & 15, g = lane >> 4;
  const int wr = w >> 1, wc = w & 1;
  const int sw = (n & 7) << 3;
  fx4 acc[4][4];
#pragma unroll
  for (int mt = 0; mt < 4; ++mt)
#pragma unroll
    for (int nt = 0; nt < 4; ++nt) acc[mt][nt] = fx4{0.f, 0.f, 0.f, 0.f};

  for (int k0 = 0; k0 < K; k0 += 64) {
    __syncthreads();
#pragma unroll
    for (int i = 0; i < 4; ++i) {
      int id = t + 256 * i;             // 1024 slots: row=id>>3, 16B chunk c=id&7
      int row = id >> 3, c = id & 7;
      int posa = 32 * (c >> 2) + 16 * (c & 1) + 4 * ((c >> 1) & 1);
      int swr = (row & 7) << 3;
      us8 av = *(const us8*)(A + (size_t)(m0 + row) * K + k0 + 8 * c);
      *(us4*)(As + row * 72 + (posa ^ swr))       = us4{av[0], av[1], av[2], av[3]};
      *(us4*)(As + row * 72 + ((posa + 8) ^ swr)) = us4{av[4], av[5], av[6], av[7]};
      us8 bv = *(const us8*)(Bt + (size_t)(n0 + row) * K + k0 + 8 * c);
      *(us4*)(Bs + row * 72 + (posa ^ swr))       = us4{bv[0], bv[1], bv[2], bv[3]};
      *(us4*)(Bs + row * 72 + ((posa + 8) ^ swr)) = us4{bv[4], bv[5], bv[6], bv[7]};
    }
    __syncthreads();
#pragma unroll
    for (int ks = 0; ks < 2; ++ks) {
      bf8 af[4], bfr[4];
#pragma unroll
      for (int mt = 0; mt < 4; ++mt) {
        int row = wr * 64 + mt * 16 + n;
        af[mt] = *(const bf8*)(As + row * 72 + ((32 * ks + 8 * g) ^ sw));
      }
#pragma unroll
      for (int nt = 0; nt < 4; ++nt) {
        int row = wc * 64 + nt * 16 + n;
        bfr[nt] = *(const bf8*)(Bs + row * 72 + ((32 * ks + 8 * g) ^ sw));
      }
#pragma unroll
      for (int mt = 0; mt < 4; ++mt)
#pragma unroll
        for (int nt = 0; nt < 4; ++nt)
          acc[mt][nt] = __builtin_amdgcn_mfma_f32_16x16x32_bf16(af[mt], bfr[nt], acc[mt][nt], 0, 0, 0);
    }
  }
#pragma unroll
  for (int mt = 0; mt < 4; ++mt)
#pragma unroll
    for (int nt = 0; nt < 4; ++nt)
#pragma unroll
      for (int r = 0; r < 4; ++r) {
        int row = m0 + wr * 64 + mt * 16 + 4 * g + r;
        int col = n0 + wc * 64 + nt * 16 + n;
        float v = acc[mt][nt][r];
        if (EPI == 1) {
          float s = v / (1.f + __expf(-v));
          ((unsigned short*)Cp)[(size_t)row * N + col] = f2bf(s);
        } else {
          ((float*)Cp)[(size_t)row * N + col] = v;
        }
      }
}

// ---------------------------------------------------------------------------
// Old 64x64 f32-input GEMM — kept for the tiny lat/k/v projections only.
// ---------------------------------------------------------------------------
template<int ABF16, int EPI>
__global__ __launch_bounds__(256) void gemm_k(const void* __restrict__ Ap,
                                              const float* __restrict__ Bp,
                                              void* __restrict__ Cp,
                                              int M, int N, int K) {
  constexpr int LDK = 68;
  __shared__ unsigned short As[64 * LDK];
  __shared__ unsigned short Bs[64 * LDK];
  const int t = threadIdx.x;
  const int m0 = blockIdx.x * 64, n0 = blockIdx.y * 64;
  const int lane = t & 63, w = t >> 6;
  const int m16 = lane & 15, g = lane >> 4;
  const int arow = w * 16 + m16;
  fx4 acc[4] = {{0.f,0.f,0.f,0.f},{0.f,0.f,0.f,0.f},{0.f,0.f,0.f,0.f},{0.f,0.f,0.f,0.f}};

  for (int k0 = 0; k0 < K; k0 += 64) {
    __syncthreads();
#pragma unroll
    for (int i = 0; i < 4; ++i) {
      int id = t * 4 + i;
      int row = id >> 4, cg = (id & 15) * 4;
      if (ABF16) {
        const unsigned short* A = (const unsigned short*)Ap;
        *(us4*)(As + row * LDK + cg) =
            *(const us4*)(A + (size_t)(m0 + row) * K + k0 + cg);
      } else {
        const float* A = (const float*)Ap;
        fx4 a = *(const fx4*)(A + (size_t)(m0 + row) * K + k0 + cg);
        us4 ab = { f2bf(a[0]), f2bf(a[1]), f2bf(a[2]), f2bf(a[3]) };
        *(us4*)(As + row * LDK + cg) = ab;
      }
      fx4 bv = *(const fx4*)(Bp + (size_t)(k0 + row) * N + n0 + cg);
      Bs[(cg + 0) * LDK + row] = f2bf(bv[0]);
      Bs[(cg + 1) * LDK + row] = f2bf(bv[1]);
      Bs[(cg + 2) * LDK + row] = f2bf(bv[2]);
      Bs[(cg + 3) * LDK + row] = f2bf(bv[3]);
    }
    __syncthreads();
#pragma unroll
    for (int ks = 0; ks < 2; ++ks) {
      const int kb = ks * 32;
      us4 a0 = *(const us4*)(As + arow * LDK + kb + 4 * g);
      us4 a1 = *(const us4*)(As + arow * LDK + kb + 16 + 4 * g);
      bf8 af;
      af[0] = (short)a0[0]; af[1] = (short)a0[1]; af[2] = (short)a0[2]; af[3] = (short)a0[3];
      af[4] = (short)a1[0]; af[5] = (short)a1[1]; af[6] = (short)a1[2]; af[7] = (short)a1[3];
#pragma unroll
      for (int nt = 0; nt < 4; ++nt) {
        const int brow = nt * 16 + m16;
        us4 b0 = *(const us4*)(Bs + brow * LDK + kb + 4 * g);
        us4 b1 = *(const us4*)(Bs + brow * LDK + kb + 16 + 4 * g);
        bf8 bf_;
        bf_[0] = (short)b0[0]; bf_[1] = (short)b0[1]; bf_[2] = (short)b0[2]; bf_[3] = (short)b0[3];
        bf_[4] = (short)b1[0]; bf_[5] = (short)b1[1]; bf_[6] = (short)b1[2]; bf_[7] = (short)b1[3];
        acc[nt] = __builtin_amdgcn_mfma_f32_16x16x32_bf16(af, bf_, acc[nt], 0, 0, 0);
      }
    }
  }
#pragma unroll
  for (int nt = 0; nt < 4; ++nt) {
#pragma unroll
    for (int r = 0; r < 4; ++r) {
      int row = m0 + w * 16 + 4 * g + r;
      int col = n0 + nt * 16 + m16;
      float vv = acc[nt][r];
      if (EPI == 1) {
        float s = vv / (1.f + __expf(-vv));
        ((unsigned short*)Cp)[(size_t)row * N + col] = f2bf(s);
      } else {
        ((float*)Cp)[(size_t)row * N + col] = vv;
      }
    }
  }
}

// ---------------------------------------------------------------------------
// In-place RoPE over x[(b,t,heads,64)]: pair (i, i+32), i<32.
// ---------------------------------------------------------------------------
__global__ void rope_k(float* __restrict__ x, int nheads, int total) {
  int idx = blockIdx.x * 256 + threadIdx.x;
  if (idx >= total) return;
  int i = idx & 31;
  int rest = idx >> 5;
  int tpos = (rest / nheads) % NT;
  float* p = x + (size_t)rest * NDH;
  float ang = (float)tpos * powf(10000.0f, -(float)i * (1.0f / 32.0f));
  float sn, cs;
  sincosf(ang, &sn, &cs);
  float x1 = p[i], x2 = p[i + 32];
  p[i]      = x1 * cs - x2 * sn;
  p[i + 32] = x2 * cs + x1 * sn;
}

// ---------------------------------------------------------------------------
// MFMA flash attention (causal, GQA) + fused sigmoid gate.
// Identical to round-2/3 version except: output is bf16 (feeds FFN1's A).
// ---------------------------------------------------------------------------
__global__ __launch_bounds__(256) void attn_mfma_k(const float* __restrict__ qb,
                                                   const float* __restrict__ kb,
                                                   const float* __restrict__ vb,
                                                   const float* __restrict__ Wg,
                                                   const float* __restrict__ bg,
                                                   unsigned short* __restrict__ outp) {
  __shared__ __align__(16) char smem[45056];
  unsigned short* Qs = (unsigned short*)smem;            //  9216 B [64][72]
  unsigned short* Ks = Qs + 64 * 72;                     //  9216 B
  unsigned short* Vt = Ks + 64 * 72;                     //  9216 B
  float* wgs  = (float*)(smem + 27648);                  // 17408 B [64][68] f32
  float* outs = (float*)smem;                            // epilogue: aliases Qs+Ks

  const int t = threadIdx.x;
  const int q0 = blockIdx.x * 64;
  const int bh = blockIdx.y;
  const int b = bh >> 4, h = bh & 15, kvh = h >> 2;
  const int lane = t & 63, wq = t >> 6;
  const int n = lane & 15, g = lane >> 4;
  const int sw = (n & 7) << 3;               // row-XOR swizzle for frag reads

  // ---- stage Wgate (f32) and Q tile (bf16, fragment order) ----
#pragma unroll
  for (int i = 0; i < 16; ++i) {
    int id = t + 256 * i;
    wgs[(id >> 6) * 68 + (id & 63)] = Wg[id];
  }
#pragma unroll
  for (int i = 0; i < 4; ++i) {
    int id = t + 256 * i;                    // 0..1023
    int row = id >> 4, c = id & 15;
    fx4 a = *(const fx4*)(qb + (((size_t)b * NT + q0 + row) * NH + h) * NDH + 4 * c);
    int pos = 32 * (c >> 3) + 8 * (c & 3) + 4 * ((c >> 2) & 1);
    us4 ab = { f2bf(a[0]), f2bf(a[1]), f2bf(a[2]), f2bf(a[3]) };
    *(us4*)(Qs + row * 72 + (pos ^ ((row & 7) << 3))) = ab;
  }
  __syncthreads();

  // ---- Q B-fragments (held for the whole KV loop) ----
  const int qrow_l = wq * 16 + n;
  bf8 bq0 = *(const bf8*)(Qs + qrow_l * 72 + ((8 * g) ^ sw));
  bf8 bq1 = *(const bf8*)(Qs + qrow_l * 72 + ((32 | (8 * g)) ^ sw));

  float mrun = -INFINITY, lsum = 0.f;
  fx4 oacc[4] = {{0.f,0.f,0.f,0.f},{0.f,0.f,0.f,0.f},{0.f,0.f,0.f,0.f},{0.f,0.f,0.f,0.f}};

  for (int s0 = 0; s0 <= q0; s0 += 64) {
    __syncthreads();
    // ---- stage K (fragment order) and V (transposed, fragment order) ----
#pragma unroll
    for (int i = 0; i < 4; ++i) {
      int id = t + 256 * i;
      int row = id >> 4, c = id & 15;
      const size_t base = (((size_t)b * NT + s0 + row) * NHKV + kvh) * NDH + 4 * c;
      fx4 kvv = *(const fx4*)(kb + base);
      int pos = 32 * (c >> 3) + 8 * (c & 3) + 4 * ((c >> 2) & 1);
      us4 ab = { f2bf(kvv[0]), f2bf(kvv[1]), f2bf(kvv[2]), f2bf(kvv[3]) };
      *(us4*)(Ks + row * 72 + (pos ^ ((row & 7) << 3))) = ab;
      fx4 vv = *(const fx4*)(vb + base);
      int sposr = 32 * (row >> 5) + 8 * ((row & 15) >> 2) + 4 * ((row >> 4) & 1) + (row & 3);
#pragma unroll
      for (int e = 0; e < 4; ++e) {
        int d = 4 * c + e;
        Vt[d * 72 + (sposr ^ ((d & 7) << 3))] = f2bf(vv[e]);
      }
    }
    __syncthreads();

    // ---- QK^T (swapped): S^T tile, per-lane 16 scores of q-row (16wq+n) ----
    float sc[16];
#pragma unroll
    for (int nt = 0; nt < 4; ++nt) {
      const int krow = 16 * nt + n;
      bf8 ka0 = *(const bf8*)(Ks + krow * 72 + ((8 * g) ^ sw));
      bf8 ka1 = *(const bf8*)(Ks + krow * 72 + ((32 | (8 * g)) ^ sw));
      fx4 s4 = {0.f, 0.f, 0.f, 0.f};
      s4 = __builtin_amdgcn_mfma_f32_16x16x32_bf16(ka0, bq0, s4, 0, 0, 0);
      s4 = __builtin_amdgcn_mfma_f32_16x16x32_bf16(ka1, bq1, s4, 0, 0, 0);
#pragma unroll
      for (int r = 0; r < 4; ++r) sc[nt * 4 + r] = s4[r] * 0.125f;
    }
    // causal mask (only the diagonal tile needs it)
    if (s0 == q0) {
#pragma unroll
      for (int nt = 0; nt < 4; ++nt)
#pragma unroll
        for (int r = 0; r < 4; ++r)
          if (16 * nt + 4 * g + r > wq * 16 + n) sc[nt * 4 + r] = -INFINITY;
    }

    // ---- online softmax (per-lane scalar state; reduce over g-groups) ----
    float tm = sc[0];
#pragma unroll
    for (int i = 1; i < 16; ++i) tm = fmaxf(tm, sc[i]);
    tm = fmaxf(tm, __shfl_xor(tm, 16));
    tm = fmaxf(tm, __shfl_xor(tm, 32));
    float mnew = fmaxf(mrun, tm);
    float corr = __expf(mrun - mnew);
    float p[16];
    float ls = 0.f;
#pragma unroll
    for (int i = 0; i < 16; ++i) { p[i] = __expf(sc[i] - mnew); ls += p[i]; }
    ls += __shfl_xor(ls, 16);
    ls += __shfl_xor(ls, 32);
    lsum = lsum * corr + ls;
    mrun = mnew;
#pragma unroll
    for (int dt = 0; dt < 4; ++dt) oacc[dt] *= corr;

    // ---- P -> bf16 B-fragments (layout already matches; no shuffles) ----
    bf8 pb0, pb1;
#pragma unroll
    for (int j = 0; j < 8; ++j) {
      pb0[j] = (short)f2bf(p[j]);
      pb1[j] = (short)f2bf(p[8 + j]);
    }

    // ---- PV (swapped): oacc[dt] += V^T * P^T ----
#pragma unroll
    for (int dt = 0; dt < 4; ++dt) {
      const int vrow = 16 * dt + n;
      bf8 va0 = *(const bf8*)(Vt + vrow * 72 + ((8 * g) ^ sw));
      bf8 va1 = *(const bf8*)(Vt + vrow * 72 + ((32 | (8 * g)) ^ sw));
      oacc[dt] = __builtin_amdgcn_mfma_f32_16x16x32_bf16(va0, pb0, oacc[dt], 0, 0, 0);
      oacc[dt] = __builtin_amdgcn_mfma_f32_16x16x32_bf16(va1, pb1, oacc[dt], 0, 0, 0);
    }
  }

  // ---- normalize and park O tile in LDS (aliases dead Qs/Ks) ----
  __syncthreads();
  const float inv = 1.0f / lsum;
#pragma unroll
  for (int dt = 0; dt < 4; ++dt)
#pragma unroll
    for (int r = 0; r < 4; ++r)
      outs[(16 * wq + n) * 68 + 16 * dt + 4 * g + r] = oacc[dt][r] * inv;
  __syncthreads();

  // ---- fused sigmoid gate epilogue (bf16 output) ----
  const int r = t >> 2, qd = t & 3;
  fx4 gs[4];
#pragma unroll
  for (int j = 0; j < 4; ++j) gs[j] = *(const fx4*)(bg + qd * 16 + j * 4);
  for (int d = 0; d < 64; ++d) {
    float od = outs[r * 68 + d];
    const float* wr = wgs + d * 68 + qd * 16;
#pragma unroll
    for (int j = 0; j < 4; ++j) gs[j] += *(const fx4*)(wr + j * 4) * od;
  }
  unsigned short* op = outp + ((size_t)b * NT + q0 + r) * NDM + h * NDH + qd * 16;
#pragma unroll
  for (int j = 0; j < 4; ++j) {
    fx4 o = *(const fx4*)(outs + r * 68 + qd * 16 + j * 4);
    us4 rb;
#pragma unroll
    for (int e = 0; e < 4; ++e) {
      float gv = 1.f / (1.f + __expf(-gs[j][e]));
      rb[e] = f2bf(o[e] * gv);
    }
    *(us4*)(op + j * 4) = rb;
  }
}

// ---------------------------------------------------------------------------
extern "C" void kernel_launch(void* const* d_in, const int* in_sizes, int n_in,
                              void* d_out, int out_size, void* d_ws, size_t ws_size,
                              hipStream_t stream) {
  const float* x    = (const float*)d_in[0];
  const float* Wq   = (const float*)d_in[1];
  const float* Wkvd = (const float*)d_in[2];
  const float* Wku  = (const float*)d_in[3];
  const float* Wvu  = (const float*)d_in[4];
  const float* Wg   = (const float*)d_in[5];
  const float* bg   = (const float*)d_in[6];
  const float* Wo1  = (const float*)d_in[7];
  const float* Wo2  = (const float*)d_in[8];
  float* out = (float*)d_out;
  char* ws = (char*)d_ws;

  // workspace layout (bytes); hbuf aliases q..xb (all dead before FFN1)
  float*          q     = (float*)(ws);                         // 16 MB f32
  float*          lat   = (float*)(ws + 16777216);              //  1 MB
  float*          kk    = (float*)(ws + 17825792);              //  4 MB
  float*          vv    = (float*)(ws + 22020096);              //  4 MB
  unsigned short* xb    = (unsigned short*)(ws + 26214400);     //  8 MB bf16
  unsigned short* hbuf  = (unsigned short*)(ws);                // 32 MB bf16 (alias)
  unsigned short* WqT   = (unsigned short*)(ws + 34602880);     //  2 MB bf16 [N,K]
  unsigned short* Wo1T  = (unsigned short*)(ws + 36700160);     //  8 MB bf16 [4096,1024]
  unsigned short* Wo2T  = (unsigned short*)(ws + 45088768);     //  8 MB bf16 [1024,4096]
  unsigned short* aob   = (unsigned short*)(ws + 53477376);     //  8 MB bf16

  const int MT = NB * NT;  // 4096 token rows
  dim3 blk(256);

  // bf16 pre-conversion (re-poisoned ws => every call)
  conv_bf_k<<<dim3(MT * NDM / 8 / 256), blk, 0, stream>>>(x, xb, MT * NDM / 8);
  convT_bf_k<<<dim3(NDM / 64, NDM / 64),  blk, 0, stream>>>(Wq,  WqT,  NDM, NDM);
  convT_bf_k<<<dim3(NDM / 64, NDFF / 64), blk, 0, stream>>>(Wo1, Wo1T, NDM, NDFF);
  convT_bf_k<<<dim3(NDFF / 64, NDM / 64), blk, 0, stream>>>(Wo2, Wo2T, NDFF, NDM);

  // projections
  gemm_bf_k<0><<<dim3(MT/128, NDM/128), blk, 0, stream>>>(xb, WqT, (void*)q, MT, NDM, NDM);
  gemm_k<0,0><<<dim3(MT/64, NLAT/64), blk, 0, stream>>>((const void*)x,   Wkvd, (void*)lat, MT, NLAT,      NDM);
  gemm_k<0,0><<<dim3(MT/64, (NHKV*NDH)/64), blk, 0, stream>>>((const void*)lat, Wku, (void*)kk, MT, NHKV*NDH, NLAT);
  gemm_k<0,0><<<dim3(MT/64, (NHKV*NDH)/64), blk, 0, stream>>>((const void*)lat, Wvu, (void*)vv, MT, NHKV*NDH, NLAT);

  int qpairs = NB * NT * NH * 32;
  int kpairs = NB * NT * NHKV * 32;
  rope_k<<<dim3((qpairs + 255) / 256), blk, 0, stream>>>(q,  NH,   qpairs);
  rope_k<<<dim3((kpairs + 255) / 256), blk, 0, stream>>>(kk, NHKV, kpairs);

  attn_mfma_k<<<dim3(NT/64, NB*NH), blk, 0, stream>>>(q, kk, vv, Wg, bg, aob);

  // FFN
  gemm_bf_k<1><<<dim3(MT/128, NDFF/128), blk, 0, stream>>>(aob,  Wo1T, (void*)hbuf, MT, NDFF, NDM);
  gemm_bf_k<0><<<dim3(MT/128, NDM/128),  blk, 0, stream>>>(hbuf, Wo2T, (void*)out,  MT, NDM,  NDFF);
}

// Round 7
// 459.015 us; speedup vs baseline: 2.5638x; 1.1633x over previous
//
#include <hip/hip_runtime.h>
#include <math.h>

#define NB 2
#define NT 2048
#define NDM 1024
#define NH 16
#define NHKV 4
#define NDH 64
#define NLAT 64
#define NDFF 4096

typedef __attribute__((ext_vector_type(4))) float fx4;
typedef __attribute__((ext_vector_type(8))) short bf8;
typedef __attribute__((ext_vector_type(4))) unsigned short us4;
typedef __attribute__((ext_vector_type(8))) unsigned short us8;

__device__ __forceinline__ unsigned short f2bf(float f) {
  union { float f; unsigned int u; } v; v.f = f;
  unsigned int u = v.u;
  u += 0x7fffu + ((u >> 16) & 1u);   // round-to-nearest-even
  return (unsigned short)(u >> 16);
}
__device__ __forceinline__ float bf2f(unsigned short h) {
  union { unsigned u; float f; } v; v.u = ((unsigned)h) << 16; return v.f;
}

// ---------------------------------------------------------------------------
// f32 -> bf16 elementwise (8 elems/thread)
// ---------------------------------------------------------------------------
__global__ void conv_bf_k(const float* __restrict__ in,
                          unsigned short* __restrict__ out, int n8) {
  int idx = blockIdx.x * 256 + threadIdx.x;
  if (idx >= n8) return;
  fx4 a = *(const fx4*)(in + (size_t)idx * 8);
  fx4 b = *(const fx4*)(in + (size_t)idx * 8 + 4);
  us8 o = { f2bf(a[0]), f2bf(a[1]), f2bf(a[2]), f2bf(a[3]),
            f2bf(b[0]), f2bf(b[1]), f2bf(b[2]), f2bf(b[3]) };
  *(us8*)(out + (size_t)idx * 8) = o;
}

// ---------------------------------------------------------------------------
// Transpose-convert: W[K,N] f32 -> Wt[N,K] bf16. 64x64 tile per block via LDS.
// ---------------------------------------------------------------------------
__global__ __launch_bounds__(256) void convT_bf_k(const float* __restrict__ W,
                                                  unsigned short* __restrict__ Wt,
                                                  int K, int N) {
  __shared__ float tile[64 * 65];
  const int t = threadIdx.x;
  const int k0 = blockIdx.x * 64, n0 = blockIdx.y * 64;
#pragma unroll
  for (int i = 0; i < 4; ++i) {
    int id = t + 256 * i;
    int row = id >> 4, c = (id & 15) * 4;
    fx4 v = *(const fx4*)(W + (size_t)(k0 + row) * N + n0 + c);
    tile[row * 65 + c + 0] = v[0];
    tile[row * 65 + c + 1] = v[1];
    tile[row * 65 + c + 2] = v[2];
    tile[row * 65 + c + 3] = v[3];
  }
  __syncthreads();
  const int nr = t >> 2, kc = (t & 3) * 16;
  us8 o0, o1;
#pragma unroll
  for (int e = 0; e < 8; ++e) o0[e] = f2bf(tile[(kc + e) * 65 + nr]);
#pragma unroll
  for (int e = 0; e < 8; ++e) o1[e] = f2bf(tile[(kc + 8 + e) * 65 + nr]);
  *(us8*)(Wt + (size_t)(n0 + nr) * K + k0 + kc) = o0;
  *(us8*)(Wt + (size_t)(n0 + nr) * K + k0 + kc + 8) = o1;
}

// ---------------------------------------------------------------------------
// bf16 GEMM, 128x128 tile, BK=64, 4 waves (each a 64x64 quadrant), staged via
// global_load_lds width=16 (m97 rung). LDS rows: 64 bf16 = 128 B = 8 slots of
// 16 B, slot-XOR swizzled: LDS slot s holds global slot s ^ (row&7) (achieved
// by pre-swizzling the per-lane SOURCE address; dest stays linear). Fragment
// reads: 2x ds_read_b64 -> conflict-free (XOR spans all 8 slots over n).
// A[M,K] bf16 row-major; Bt[N,K] bf16 row-major. EPI=0: f32 C; 1: bf16(silu).
// ---------------------------------------------------------------------------
__device__ __forceinline__ bf8 fragG(const unsigned short* base, int row, int gr) {
  const unsigned short* rb = base + row * 64;
  const int r7 = row & 7;
  us4 lo = *(const us4*)(rb + 8 * ((gr >> 1) ^ r7) + 4 * (gr & 1));
  us4 hi = *(const us4*)(rb + 8 * (((gr + 4) >> 1) ^ r7) + 4 * (gr & 1));
  bf8 f;
  f[0] = (short)lo[0]; f[1] = (short)lo[1]; f[2] = (short)lo[2]; f[3] = (short)lo[3];
  f[4] = (short)hi[0]; f[5] = (short)hi[1]; f[6] = (short)hi[2]; f[7] = (short)hi[3];
  return f;
}

template<int EPI>
__global__ __launch_bounds__(256) void gemm_bf_k(const unsigned short* __restrict__ A,
                                                 const unsigned short* __restrict__ Bt,
                                                 void* __restrict__ Cp,
                                                 int M, int N, int K) {
  __shared__ __align__(16) unsigned short As[128 * 64];
  __shared__ __align__(16) unsigned short Bs[128 * 64];
  const int t = threadIdx.x;
  const int m0 = blockIdx.x * 128, n0 = blockIdx.y * 128;
  const int lane = t & 63, w = t >> 6;
  const int n = lane & 15, g = lane >> 4;
  const int wr = w >> 1, wc = w & 1;
  const int lrow = lane >> 3;                 // 0..7 within 8-row group
  const int lslot = (lane & 7) ^ lrow;        // pre-swizzled source slot
  const unsigned short* srcA = A  + (size_t)(m0 + 32 * w + lrow) * K + 8 * lslot;
  const unsigned short* srcB = Bt + (size_t)(n0 + 32 * w + lrow) * K + 8 * lslot;
  fx4 acc[4][4];
#pragma unroll
  for (int mt = 0; mt < 4; ++mt)
#pragma unroll
    for (int nt = 0; nt < 4; ++nt) acc[mt][nt] = fx4{0.f, 0.f, 0.f, 0.f};

  for (int k0 = 0; k0 < K; k0 += 64) {
    __syncthreads();
#pragma unroll
    for (int u = 0; u < 4; ++u) {
      __builtin_amdgcn_global_load_lds(
          (const __attribute__((address_space(1))) unsigned int*)(srcA + (size_t)(8 * u) * K + k0),
          (__attribute__((address_space(3))) unsigned int*)(As + (32 * w + 8 * u) * 64),
          16, 0, 0);
      __builtin_amdgcn_global_load_lds(
          (const __attribute__((address_space(1))) unsigned int*)(srcB + (size_t)(8 * u) * K + k0),
          (__attribute__((address_space(3))) unsigned int*)(Bs + (32 * w + 8 * u) * 64),
          16, 0, 0);
    }
    __syncthreads();
#pragma unroll
    for (int ks = 0; ks < 2; ++ks) {
      bf8 af[4], bfr[4];
#pragma unroll
      for (int mt = 0; mt < 4; ++mt)
        af[mt] = fragG(As, wr * 64 + mt * 16 + n, 8 * ks + g);
#pragma unroll
      for (int nt = 0; nt < 4; ++nt)
        bfr[nt] = fragG(Bs, wc * 64 + nt * 16 + n, 8 * ks + g);
#pragma unroll
      for (int mt = 0; mt < 4; ++mt)
#pragma unroll
        for (int nt = 0; nt < 4; ++nt)
          acc[mt][nt] = __builtin_amdgcn_mfma_f32_16x16x32_bf16(af[mt], bfr[nt], acc[mt][nt], 0, 0, 0);
    }
  }
#pragma unroll
  for (int mt = 0; mt < 4; ++mt)
#pragma unroll
    for (int nt = 0; nt < 4; ++nt)
#pragma unroll
      for (int r = 0; r < 4; ++r) {
        int row = m0 + wr * 64 + mt * 16 + 4 * g + r;
        int col = n0 + wc * 64 + nt * 16 + n;
        float v = acc[mt][nt][r];
        if (EPI == 1) {
          float s = v / (1.f + __expf(-v));
          ((unsigned short*)Cp)[(size_t)row * N + col] = f2bf(s);
        } else {
          ((float*)Cp)[(size_t)row * N + col] = v;
        }
      }
}

// ---------------------------------------------------------------------------
// Old 64x64 f32-input GEMM — kept for the tiny lat/k/v projections only.
// ---------------------------------------------------------------------------
template<int ABF16, int EPI>
__global__ __launch_bounds__(256) void gemm_k(const void* __restrict__ Ap,
                                              const float* __restrict__ Bp,
                                              void* __restrict__ Cp,
                                              int M, int N, int K) {
  constexpr int LDK = 68;
  __shared__ unsigned short As[64 * LDK];
  __shared__ unsigned short Bs[64 * LDK];
  const int t = threadIdx.x;
  const int m0 = blockIdx.x * 64, n0 = blockIdx.y * 64;
  const int lane = t & 63, w = t >> 6;
  const int m16 = lane & 15, g = lane >> 4;
  const int arow = w * 16 + m16;
  fx4 acc[4] = {{0.f,0.f,0.f,0.f},{0.f,0.f,0.f,0.f},{0.f,0.f,0.f,0.f},{0.f,0.f,0.f,0.f}};

  for (int k0 = 0; k0 < K; k0 += 64) {
    __syncthreads();
#pragma unroll
    for (int i = 0; i < 4; ++i) {
      int id = t * 4 + i;
      int row = id >> 4, cg = (id & 15) * 4;
      if (ABF16) {
        const unsigned short* A = (const unsigned short*)Ap;
        *(us4*)(As + row * LDK + cg) =
            *(const us4*)(A + (size_t)(m0 + row) * K + k0 + cg);
      } else {
        const float* A = (const float*)Ap;
        fx4 a = *(const fx4*)(A + (size_t)(m0 + row) * K + k0 + cg);
        us4 ab = { f2bf(a[0]), f2bf(a[1]), f2bf(a[2]), f2bf(a[3]) };
        *(us4*)(As + row * LDK + cg) = ab;
      }
      fx4 bv = *(const fx4*)(Bp + (size_t)(k0 + row) * N + n0 + cg);
      Bs[(cg + 0) * LDK + row] = f2bf(bv[0]);
      Bs[(cg + 1) * LDK + row] = f2bf(bv[1]);
      Bs[(cg + 2) * LDK + row] = f2bf(bv[2]);
      Bs[(cg + 3) * LDK + row] = f2bf(bv[3]);
    }
    __syncthreads();
#pragma unroll
    for (int ks = 0; ks < 2; ++ks) {
      const int kb = ks * 32;
      us4 a0 = *(const us4*)(As + arow * LDK + kb + 4 * g);
      us4 a1 = *(const us4*)(As + arow * LDK + kb + 16 + 4 * g);
      bf8 af;
      af[0] = (short)a0[0]; af[1] = (short)a0[1]; af[2] = (short)a0[2]; af[3] = (short)a0[3];
      af[4] = (short)a1[0]; af[5] = (short)a1[1]; af[6] = (short)a1[2]; af[7] = (short)a1[3];
#pragma unroll
      for (int nt = 0; nt < 4; ++nt) {
        const int brow = nt * 16 + m16;
        us4 b0 = *(const us4*)(Bs + brow * LDK + kb + 4 * g);
        us4 b1 = *(const us4*)(Bs + brow * LDK + kb + 16 + 4 * g);
        bf8 bf_;
        bf_[0] = (short)b0[0]; bf_[1] = (short)b0[1]; bf_[2] = (short)b0[2]; bf_[3] = (short)b0[3];
        bf_[4] = (short)b1[0]; bf_[5] = (short)b1[1]; bf_[6] = (short)b1[2]; bf_[7] = (short)b1[3];
        acc[nt] = __builtin_amdgcn_mfma_f32_16x16x32_bf16(af, bf_, acc[nt], 0, 0, 0);
      }
    }
  }
#pragma unroll
  for (int nt = 0; nt < 4; ++nt) {
#pragma unroll
    for (int r = 0; r < 4; ++r) {
      int row = m0 + w * 16 + 4 * g + r;
      int col = n0 + nt * 16 + m16;
      float vv = acc[nt][r];
      if (EPI == 1) {
        float s = vv / (1.f + __expf(-vv));
        ((unsigned short*)Cp)[(size_t)row * N + col] = f2bf(s);
      } else {
        ((float*)Cp)[(size_t)row * N + col] = vv;
      }
    }
  }
}

// ---------------------------------------------------------------------------
// In-place RoPE over x[(b,t,heads,64)]: pair (i, i+32), i<32.
// ---------------------------------------------------------------------------
__global__ void rope_k(float* __restrict__ x, int nheads, int total) {
  int idx = blockIdx.x * 256 + threadIdx.x;
  if (idx >= total) return;
  int i = idx & 31;
  int rest = idx >> 5;
  int tpos = (rest / nheads) % NT;
  float* p = x + (size_t)rest * NDH;
  float ang = (float)tpos * powf(10000.0f, -(float)i * (1.0f / 32.0f));
  float sn, cs;
  sincosf(ang, &sn, &cs);
  float x1 = p[i], x2 = p[i + 32];
  p[i]      = x1 * cs - x2 * sn;
  p[i + 32] = x2 * cs + x1 * sn;
}

// ---------------------------------------------------------------------------
// MFMA flash attention (causal, GQA) + fused sigmoid gate.  Round-6 layout:
// LINEAR LDS rows (72 u16 = 144 B stride; k/key order, NO swizzle).
//   Fragment read = 2x ds_read_b64 at bank 4(n&7)+const -> 2-way (free).
// V transposed IN-REGISTER (4x4 across lanes g via 4 shfl_xor), then one us4
//   write per lane (+8 u16 shift on odd d-octets to spread banks -> 4-way).
// Swapped-operand MFMA scheme: S^T = mfma(K, Q); O^T = mfma(V^T, P^T).
// Lane (g=lane>>4, n=lane&15) of wave wq: scores S[q=16wq+n][key=16nt+4g+r];
// per-lane scalar softmax state; P regs feed PV's B-operand directly.
// ---------------------------------------------------------------------------
__device__ __forceinline__ bf8 frag64(const unsigned short* base, int row, int gr) {
  const unsigned short* rb = base + row * 72;
  us4 lo = *(const us4*)(rb + 4 * gr);
  us4 hi = *(const us4*)(rb + 4 * gr + 16);
  bf8 f;
  f[0] = (short)lo[0]; f[1] = (short)lo[1]; f[2] = (short)lo[2]; f[3] = (short)lo[3];
  f[4] = (short)hi[0]; f[5] = (short)hi[1]; f[6] = (short)hi[2]; f[7] = (short)hi[3];
  return f;
}
__device__ __forceinline__ bf8 frag64v(const unsigned short* base, int row, int gr) {
  const unsigned short* rb = base + row * 72 + 8 * ((row >> 3) & 1);
  us4 lo = *(const us4*)(rb + 4 * gr);
  us4 hi = *(const us4*)(rb + 4 * gr + 16);
  bf8 f;
  f[0] = (short)lo[0]; f[1] = (short)lo[1]; f[2] = (short)lo[2]; f[3] = (short)lo[3];
  f[4] = (short)hi[0]; f[5] = (short)hi[1]; f[6] = (short)hi[2]; f[7] = (short)hi[3];
  return f;
}

__global__ __launch_bounds__(256) void attn_mfma_k(const float* __restrict__ qb,
                                                   const float* __restrict__ kb,
                                                   const float* __restrict__ vb,
                                                   const float* __restrict__ Wg,
                                                   const float* __restrict__ bg,
                                                   unsigned short* __restrict__ outp) {
  __shared__ __align__(16) char smem[36352];
  unsigned short* Qs  = (unsigned short*)smem;        // [64][72] 9216 B
  unsigned short* Ks  = Qs + 64 * 72;                 // 9216 B
  unsigned short* Vt  = Ks + 64 * 72;                 // 9216 B  (V^T: rows=d)
  unsigned short* wgs = Vt + 64 * 72;                 // [64][68] bf16 8704 B
  float* outs = (float*)smem;                         // epilogue: aliases Qs+Ks

  const int t = threadIdx.x;
  const int q0 = blockIdx.x * 64;
  const int bh = blockIdx.y;
  const int b = bh >> 4, h = bh & 15, kvh = h >> 2;
  const int lane = t & 63, wq = t >> 6;
  const int n = lane & 15, g = lane >> 4;
  const int srow = 4 * wq + g;            // staging row base (i=0), this lane
  const int c = n;                        // staging column group

  // ---- stage Wgate (bf16) and Q tile (bf16, linear rows) ----
#pragma unroll
  for (int i = 0; i < 4; ++i) {
    int id = t + 256 * i;                 // 0..1023 us4-chunks
    int row = id >> 4, cc = id & 15;
    fx4 wv = *(const fx4*)(Wg + (size_t)id * 4);
    us4 wb = { f2bf(wv[0]), f2bf(wv[1]), f2bf(wv[2]), f2bf(wv[3]) };
    *(us4*)(wgs + row * 68 + 4 * cc) = wb;
    fx4 a = *(const fx4*)(qb + (((size_t)b * NT + q0 + row) * NH + h) * NDH + 4 * cc);
    us4 ab = { f2bf(a[0]), f2bf(a[1]), f2bf(a[2]), f2bf(a[3]) };
    *(us4*)(Qs + row * 72 + 4 * cc) = ab;
  }
  __syncthreads();

  // ---- Q B-fragments (held for the whole KV loop) ----
  const int qrow_l = wq * 16 + n;
  bf8 bq0 = frag64(Qs, qrow_l, g);
  bf8 bq1 = frag64(Qs, qrow_l, g + 8);

  float mrun = -INFINITY, lsum = 0.f;
  fx4 oacc[4] = {{0.f,0.f,0.f,0.f},{0.f,0.f,0.f,0.f},{0.f,0.f,0.f,0.f},{0.f,0.f,0.f,0.f}};

  for (int s0 = 0; s0 <= q0; s0 += 64) {
    __syncthreads();
    // ---- stage K (linear) and V (in-register 4x4 transpose -> V^T) ----
#pragma unroll
    for (int i = 0; i < 4; ++i) {
      const int row = srow + 16 * i;      // key row 0..63
      const size_t base = (((size_t)b * NT + s0 + row) * NHKV + kvh) * NDH + 4 * c;
      fx4 kv4 = *(const fx4*)(kb + base);
      us4 ab = { f2bf(kv4[0]), f2bf(kv4[1]), f2bf(kv4[2]), f2bf(kv4[3]) };
      *(us4*)(Ks + row * 72 + 4 * c) = ab;

      fx4 vv4 = *(const fx4*)(vb + base);
      float u0 = vv4[0], u1 = vv4[1], u2 = vv4[2], u3 = vv4[3];
      // 4x4 transpose across lanes g (rows=keys srow+16i+g', cols=d 4c..4c+3)
      float t0 = __shfl_xor((g & 2) ? u0 : u2, 32);
      float t1 = __shfl_xor((g & 2) ? u1 : u3, 32);
      if (g & 2) { u0 = t0; u1 = t1; } else { u2 = t0; u3 = t1; }
      float s0v = __shfl_xor((g & 1) ? u0 : u1, 16);
      float s1v = __shfl_xor((g & 1) ? u2 : u3, 16);
      if (g & 1) { u0 = s0v; u2 = s1v; } else { u1 = s0v; u3 = s1v; }
      // lane now holds V^T[d = 4c+g][keys r0..r0+3], r0 = 4wq + 16i
      const int dd = 4 * c + g;
      const int r0 = 4 * wq + 16 * i;
      us4 tv = { f2bf(u0), f2bf(u1), f2bf(u2), f2bf(u3) };
      *(us4*)(Vt + dd * 72 + 8 * ((dd >> 3) & 1) + r0) = tv;
    }
    __syncthreads();

    // ---- QK^T (swapped): per-lane 16 scores of q-row (16wq+n) ----
    float sc[16];
#pragma unroll
    for (int nt = 0; nt < 4; ++nt) {
      const int krow = 16 * nt + n;
      bf8 ka0 = frag64(Ks, krow, g);
      bf8 ka1 = frag64(Ks, krow, g + 8);
      fx4 s4 = {0.f, 0.f, 0.f, 0.f};
      s4 = __builtin_amdgcn_mfma_f32_16x16x32_bf16(ka0, bq0, s4, 0, 0, 0);
      s4 = __builtin_amdgcn_mfma_f32_16x16x32_bf16(ka1, bq1, s4, 0, 0, 0);
#pragma unroll
      for (int r = 0; r < 4; ++r) sc[nt * 4 + r] = s4[r] * 0.125f;
    }
    // causal mask (only the diagonal tile needs it)
    if (s0 == q0) {
#pragma unroll
      for (int nt = 0; nt < 4; ++nt)
#pragma unroll
        for (int r = 0; r < 4; ++r)
          if (16 * nt + 4 * g + r > wq * 16 + n) sc[nt * 4 + r] = -INFINITY;
    }

    // ---- online softmax (per-lane scalar state; reduce over g-groups) ----
    float tm = sc[0];
#pragma unroll
    for (int i = 1; i < 16; ++i) tm = fmaxf(tm, sc[i]);
    tm = fmaxf(tm, __shfl_xor(tm, 16));
    tm = fmaxf(tm, __shfl_xor(tm, 32));
    float mnew = fmaxf(mrun, tm);
    float corr = __expf(mrun - mnew);
    float p[16];
    float ls = 0.f;
#pragma unroll
    for (int i = 0; i < 16; ++i) { p[i] = __expf(sc[i] - mnew); ls += p[i]; }
    ls += __shfl_xor(ls, 16);
    ls += __shfl_xor(ls, 32);
    lsum = lsum * corr + ls;
    mrun = mnew;
#pragma unroll
    for (int dt = 0; dt < 4; ++dt) oacc[dt] *= corr;

    // ---- P -> bf16 B-fragments (layout already matches; no shuffles) ----
    bf8 pb0, pb1;
#pragma unroll
    for (int j = 0; j < 8; ++j) {
      pb0[j] = (short)f2bf(p[j]);
      pb1[j] = (short)f2bf(p[8 + j]);
    }

    // ---- PV (swapped): oacc[dt] += V^T * P^T ----
#pragma unroll
    for (int dt = 0; dt < 4; ++dt) {
      const int vrow = 16 * dt + n;
      bf8 va0 = frag64v(Vt, vrow, g);
      bf8 va1 = frag64v(Vt, vrow, g + 8);
      oacc[dt] = __builtin_amdgcn_mfma_f32_16x16x32_bf16(va0, pb0, oacc[dt], 0, 0, 0);
      oacc[dt] = __builtin_amdgcn_mfma_f32_16x16x32_bf16(va1, pb1, oacc[dt], 0, 0, 0);
    }
  }

  // ---- normalize and park O tile in LDS (aliases dead Qs/Ks) ----
  __syncthreads();
  const float inv = 1.0f / lsum;
#pragma unroll
  for (int dt = 0; dt < 4; ++dt)
#pragma unroll
    for (int r = 0; r < 4; ++r)
      outs[(16 * wq + n) * 68 + 16 * dt + 4 * g + r] = oacc[dt][r] * inv;
  __syncthreads();

  // ---- fused sigmoid gate epilogue (bf16 weights, bf16 output) ----
  const int r = t >> 2, qd = t & 3;
  fx4 gs[4];
#pragma unroll
  for (int j = 0; j < 4; ++j) gs[j] = *(const fx4*)(bg + qd * 16 + j * 4);
  for (int d = 0; d < 64; ++d) {
    float od = outs[r * 68 + d];
    const unsigned short* wr = wgs + d * 68 + qd * 16;
#pragma unroll
    for (int j = 0; j < 4; ++j) {
      us4 wv = *(const us4*)(wr + j * 4);
      gs[j][0] += bf2f(wv[0]) * od;
      gs[j][1] += bf2f(wv[1]) * od;
      gs[j][2] += bf2f(wv[2]) * od;
      gs[j][3] += bf2f(wv[3]) * od;
    }
  }
  unsigned short* op = outp + ((size_t)b * NT + q0 + r) * NDM + h * NDH + qd * 16;
#pragma unroll
  for (int j = 0; j < 4; ++j) {
    fx4 o = *(const fx4*)(outs + r * 68 + qd * 16 + j * 4);
    us4 rb;
#pragma unroll
    for (int e = 0; e < 4; ++e) {
      float gv = 1.f / (1.f + __expf(-gs[j][e]));
      rb[e] = f2bf(o[e] * gv);
    }
    *(us4*)(op + j * 4) = rb;
  }
}

// ---------------------------------------------------------------------------
extern "C" void kernel_launch(void* const* d_in, const int* in_sizes, int n_in,
                              void* d_out, int out_size, void* d_ws, size_t ws_size,
                              hipStream_t stream) {
  const float* x    = (const float*)d_in[0];
  const float* Wq   = (const float*)d_in[1];
  const float* Wkvd = (const float*)d_in[2];
  const float* Wku  = (const float*)d_in[3];
  const float* Wvu  = (const float*)d_in[4];
  const float* Wg   = (const float*)d_in[5];
  const float* bg   = (const float*)d_in[6];
  const float* Wo1  = (const float*)d_in[7];
  const float* Wo2  = (const float*)d_in[8];
  float* out = (float*)d_out;
  char* ws = (char*)d_ws;

  // workspace layout (bytes); hbuf aliases q..xb (all dead before FFN1)
  float*          q     = (float*)(ws);                         // 16 MB f32
  float*          lat   = (float*)(ws + 16777216);              //  1 MB
  float*          kk    = (float*)(ws + 17825792);              //  4 MB
  float*          vv    = (float*)(ws + 22020096);              //  4 MB
  unsigned short* xb    = (unsigned short*)(ws + 26214400);     //  8 MB bf16
  unsigned short* hbuf  = (unsigned short*)(ws);                // 32 MB bf16 (alias)
  unsigned short* WqT   = (unsigned short*)(ws + 34602880);     //  2 MB bf16 [N,K]
  unsigned short* Wo1T  = (unsigned short*)(ws + 36700160);     //  8 MB bf16 [4096,1024]
  unsigned short* Wo2T  = (unsigned short*)(ws + 45088768);     //  8 MB bf16 [1024,4096]
  unsigned short* aob   = (unsigned short*)(ws + 53477376);     //  8 MB bf16

  const int MT = NB * NT;  // 4096 token rows
  dim3 blk(256);

  // bf16 pre-conversion (ws re-poisoned => every call)
  conv_bf_k<<<dim3(MT * NDM / 8 / 256), blk, 0, stream>>>(x, xb, MT * NDM / 8);
  convT_bf_k<<<dim3(NDM / 64, NDM / 64),  blk, 0, stream>>>(Wq,  WqT,  NDM, NDM);
  convT_bf_k<<<dim3(NDM / 64, NDFF / 64), blk, 0, stream>>>(Wo1, Wo1T, NDM, NDFF);
  convT_bf_k<<<dim3(NDFF / 64, NDM / 64), blk, 0, stream>>>(Wo2, Wo2T, NDFF, NDM);

  // projections
  gemm_bf_k<0><<<dim3(MT/128, NDM/128), blk, 0, stream>>>(xb, WqT, (void*)q, MT, NDM, NDM);
  gemm_k<0,0><<<dim3(MT/64, NLAT/64), blk, 0, stream>>>((const void*)x,   Wkvd, (void*)lat, MT, NLAT,      NDM);
  gemm_k<0,0><<<dim3(MT/64, (NHKV*NDH)/64), blk, 0, stream>>>((const void*)lat, Wku, (void*)kk, MT, NHKV*NDH, NLAT);
  gemm_k<0,0><<<dim3(MT/64, (NHKV*NDH)/64), blk, 0, stream>>>((const void*)lat, Wvu, (void*)vv, MT, NHKV*NDH, NLAT);

  int qpairs = NB * NT * NH * 32;
  int kpairs = NB * NT * NHKV * 32;
  rope_k<<<dim3((qpairs + 255) / 256), blk, 0, stream>>>(q,  NH,   qpairs);
  rope_k<<<dim3((kpairs + 255) / 256), blk, 0, stream>>>(kk, NHKV, kpairs);

  attn_mfma_k<<<dim3(NT/64, NB*NH), blk, 0, stream>>>(q, kk, vv, Wg, bg, aob);

  // FFN
  gemm_bf_k<1><<<dim3(MT/128, NDFF/128), blk, 0, stream>>>(aob,  Wo1T, (void*)hbuf, MT, NDFF, NDM);
  gemm_bf_k<0><<<dim3(MT/128, NDM/128),  blk, 0, stream>>>(hbuf, Wo2T, (void*)out,  MT, NDM,  NDFF);
}

// Round 12
// 445.270 us; speedup vs baseline: 2.6429x; 1.0309x over previous
//
#include <hip/hip_runtime.h>
#include <hip/hip_bf16.h>
#include <math.h>

#define NB 2
#define NT 2048
#define NDM 1024
#define NH 16
#define NHKV 4
#define NDH 64
#define NLAT 64
#define NDFF 4096

typedef __attribute__((ext_vector_type(4))) float fx4;
typedef __attribute__((ext_vector_type(8))) short bf8;
typedef __attribute__((ext_vector_type(4))) unsigned short us4;
typedef __attribute__((ext_vector_type(8))) unsigned short us8;

// native convert -> compiler fuses pairs into v_cvt_pk_bf16_f32 (RNE)
__device__ __forceinline__ unsigned short f2bf(float f) {
  __hip_bfloat16 h = __float2bfloat16(f);
  unsigned short u;
  __builtin_memcpy(&u, &h, 2);
  return u;
}
__device__ __forceinline__ float bf2f(unsigned short h) {
  union { unsigned u; float f; } v; v.u = ((unsigned)h) << 16; return v.f;
}

// ---------------------------------------------------------------------------
// f32 -> bf16 elementwise (8 elems/thread)
// ---------------------------------------------------------------------------
__global__ void conv_bf_k(const float* __restrict__ in,
                          unsigned short* __restrict__ out, int n8) {
  int idx = blockIdx.x * 256 + threadIdx.x;
  if (idx >= n8) return;
  fx4 a = *(const fx4*)(in + (size_t)idx * 8);
  fx4 b = *(const fx4*)(in + (size_t)idx * 8 + 4);
  us8 o = { f2bf(a[0]), f2bf(a[1]), f2bf(a[2]), f2bf(a[3]),
            f2bf(b[0]), f2bf(b[1]), f2bf(b[2]), f2bf(b[3]) };
  *(us8*)(out + (size_t)idx * 8) = o;
}

// ---------------------------------------------------------------------------
// Transpose-convert: W[K,N] f32 -> Wt[N,K] bf16. 64x64 tile per block via LDS.
// ---------------------------------------------------------------------------
__global__ __launch_bounds__(256) void convT_bf_k(const float* __restrict__ W,
                                                  unsigned short* __restrict__ Wt,
                                                  int K, int N) {
  __shared__ float tile[64 * 65];
  const int t = threadIdx.x;
  const int k0 = blockIdx.x * 64, n0 = blockIdx.y * 64;
#pragma unroll
  for (int i = 0; i < 4; ++i) {
    int id = t + 256 * i;
    int row = id >> 4, c = (id & 15) * 4;
    fx4 v = *(const fx4*)(W + (size_t)(k0 + row) * N + n0 + c);
    tile[row * 65 + c + 0] = v[0];
    tile[row * 65 + c + 1] = v[1];
    tile[row * 65 + c + 2] = v[2];
    tile[row * 65 + c + 3] = v[3];
  }
  __syncthreads();
  const int nr = t >> 2, kc = (t & 3) * 16;
  us8 o0, o1;
#pragma unroll
  for (int e = 0; e < 8; ++e) o0[e] = f2bf(tile[(kc + e) * 65 + nr]);
#pragma unroll
  for (int e = 0; e < 8; ++e) o1[e] = f2bf(tile[(kc + 8 + e) * 65 + nr]);
  *(us8*)(Wt + (size_t)(n0 + nr) * K + k0 + kc) = o0;
  *(us8*)(Wt + (size_t)(n0 + nr) * K + k0 + kc + 8) = o1;
}

// ---------------------------------------------------------------------------
// bf16 GEMM, 128x128 tile, BK=64, 4 waves, global_load_lds staging (m97 rung),
// slot-XOR LDS swizzle via pre-swizzled SOURCE. + XCD-aware block swizzle (T1).
// ---------------------------------------------------------------------------
__device__ __forceinline__ bf8 fragG(const unsigned short* base, int row, int gr) {
  const unsigned short* rb = base + row * 64;
  const int r7 = row & 7;
  us4 lo = *(const us4*)(rb + 8 * ((gr >> 1) ^ r7) + 4 * (gr & 1));
  us4 hi = *(const us4*)(rb + 8 * (((gr + 4) >> 1) ^ r7) + 4 * (gr & 1));
  bf8 f;
  f[0] = (short)lo[0]; f[1] = (short)lo[1]; f[2] = (short)lo[2]; f[3] = (short)lo[3];
  f[4] = (short)hi[0]; f[5] = (short)hi[1]; f[6] = (short)hi[2]; f[7] = (short)hi[3];
  return f;
}

template<int EPI>
__global__ __launch_bounds__(256) void gemm_bf_k(const unsigned short* __restrict__ A,
                                                 const unsigned short* __restrict__ Bt,
                                                 void* __restrict__ Cp,
                                                 int M, int N, int K) {
  __shared__ __align__(16) unsigned short As[128 * 64];
  __shared__ __align__(16) unsigned short Bs[128 * 64];
  const int t = threadIdx.x;
  // XCD-aware swizzle (nwg % 8 == 0 for all our grids)
  const int nwg = gridDim.x * gridDim.y;
  int orig = blockIdx.y * gridDim.x + blockIdx.x;
  int tileid = orig;
  if ((nwg & 7) == 0) tileid = (orig & 7) * (nwg >> 3) + (orig >> 3);
  const int bxg = tileid % gridDim.x, byg = tileid / gridDim.x;
  const int m0 = bxg * 128, n0 = byg * 128;
  const int lane = t & 63, w = t >> 6;
  const int n = lane & 15, g = lane >> 4;
  const int wr = w >> 1, wc = w & 1;
  const int lrow = lane >> 3;                 // 0..7 within 8-row group
  const int lslot = (lane & 7) ^ lrow;        // pre-swizzled source slot
  const unsigned short* srcA = A  + (size_t)(m0 + 32 * w + lrow) * K + 8 * lslot;
  const unsigned short* srcB = Bt + (size_t)(n0 + 32 * w + lrow) * K + 8 * lslot;
  fx4 acc[4][4];
#pragma unroll
  for (int mt = 0; mt < 4; ++mt)
#pragma unroll
    for (int nt = 0; nt < 4; ++nt) acc[mt][nt] = fx4{0.f, 0.f, 0.f, 0.f};

  for (int k0 = 0; k0 < K; k0 += 64) {
    __syncthreads();
#pragma unroll
    for (int u = 0; u < 4; ++u) {
      __builtin_amdgcn_global_load_lds(
          (const __attribute__((address_space(1))) unsigned int*)(srcA + (size_t)(8 * u) * K + k0),
          (__attribute__((address_space(3))) unsigned int*)(As + (32 * w + 8 * u) * 64),
          16, 0, 0);
      __builtin_amdgcn_global_load_lds(
          (const __attribute__((address_space(1))) unsigned int*)(srcB + (size_t)(8 * u) * K + k0),
          (__attribute__((address_space(3))) unsigned int*)(Bs + (32 * w + 8 * u) * 64),
          16, 0, 0);
    }
    __syncthreads();
#pragma unroll
    for (int ks = 0; ks < 2; ++ks) {
      bf8 af[4], bfr[4];
#pragma unroll
      for (int mt = 0; mt < 4; ++mt)
        af[mt] = fragG(As, wr * 64 + mt * 16 + n, 8 * ks + g);
#pragma unroll
      for (int nt = 0; nt < 4; ++nt)
        bfr[nt] = fragG(Bs, wc * 64 + nt * 16 + n, 8 * ks + g);
#pragma unroll
      for (int mt = 0; mt < 4; ++mt)
#pragma unroll
        for (int nt = 0; nt < 4; ++nt)
          acc[mt][nt] = __builtin_amdgcn_mfma_f32_16x16x32_bf16(af[mt], bfr[nt], acc[mt][nt], 0, 0, 0);
    }
  }
#pragma unroll
  for (int mt = 0; mt < 4; ++mt)
#pragma unroll
    for (int nt = 0; nt < 4; ++nt)
#pragma unroll
      for (int r = 0; r < 4; ++r) {
        int row = m0 + wr * 64 + mt * 16 + 4 * g + r;
        int col = n0 + wc * 64 + nt * 16 + n;
        float v = acc[mt][nt][r];
        if (EPI == 1) {
          float s = v / (1.f + __expf(-v));
          ((unsigned short*)Cp)[(size_t)row * N + col] = f2bf(s);
        } else {
          ((float*)Cp)[(size_t)row * N + col] = v;
        }
      }
}

// ---------------------------------------------------------------------------
// Old 64x64 f32-input GEMM — tiny lat/k/v projections only.
// ---------------------------------------------------------------------------
template<int ABF16, int EPI>
__global__ __launch_bounds__(256) void gemm_k(const void* __restrict__ Ap,
                                              const float* __restrict__ Bp,
                                              void* __restrict__ Cp,
                                              int M, int N, int K) {
  constexpr int LDK = 68;
  __shared__ unsigned short As[64 * LDK];
  __shared__ unsigned short Bs[64 * LDK];
  const int t = threadIdx.x;
  const int m0 = blockIdx.x * 64, n0 = blockIdx.y * 64;
  const int lane = t & 63, w = t >> 6;
  const int m16 = lane & 15, g = lane >> 4;
  const int arow = w * 16 + m16;
  fx4 acc[4] = {{0.f,0.f,0.f,0.f},{0.f,0.f,0.f,0.f},{0.f,0.f,0.f,0.f},{0.f,0.f,0.f,0.f}};

  for (int k0 = 0; k0 < K; k0 += 64) {
    __syncthreads();
#pragma unroll
    for (int i = 0; i < 4; ++i) {
      int id = t * 4 + i;
      int row = id >> 4, cg = (id & 15) * 4;
      if (ABF16) {
        const unsigned short* A = (const unsigned short*)Ap;
        *(us4*)(As + row * LDK + cg) =
            *(const us4*)(A + (size_t)(m0 + row) * K + k0 + cg);
      } else {
        const float* A = (const float*)Ap;
        fx4 a = *(const fx4*)(A + (size_t)(m0 + row) * K + k0 + cg);
        us4 ab = { f2bf(a[0]), f2bf(a[1]), f2bf(a[2]), f2bf(a[3]) };
        *(us4*)(As + row * LDK + cg) = ab;
      }
      fx4 bv = *(const fx4*)(Bp + (size_t)(k0 + row) * N + n0 + cg);
      Bs[(cg + 0) * LDK + row] = f2bf(bv[0]);
      Bs[(cg + 1) * LDK + row] = f2bf(bv[1]);
      Bs[(cg + 2) * LDK + row] = f2bf(bv[2]);
      Bs[(cg + 3) * LDK + row] = f2bf(bv[3]);
    }
    __syncthreads();
#pragma unroll
    for (int ks = 0; ks < 2; ++ks) {
      const int kb = ks * 32;
      us4 a0 = *(const us4*)(As + arow * LDK + kb + 4 * g);
      us4 a1 = *(const us4*)(As + arow * LDK + kb + 16 + 4 * g);
      bf8 af;
      af[0] = (short)a0[0]; af[1] = (short)a0[1]; af[2] = (short)a0[2]; af[3] = (short)a0[3];
      af[4] = (short)a1[0]; af[5] = (short)a1[1]; af[6] = (short)a1[2]; af[7] = (short)a1[3];
#pragma unroll
      for (int nt = 0; nt < 4; ++nt) {
        const int brow = nt * 16 + m16;
        us4 b0 = *(const us4*)(Bs + brow * LDK + kb + 4 * g);
        us4 b1 = *(const us4*)(Bs + brow * LDK + kb + 16 + 4 * g);
        bf8 bf_;
        bf_[0] = (short)b0[0]; bf_[1] = (short)b0[1]; bf_[2] = (short)b0[2]; bf_[3] = (short)b0[3];
        bf_[4] = (short)b1[0]; bf_[5] = (short)b1[1]; bf_[6] = (short)b1[2]; bf_[7] = (short)b1[3];
        acc[nt] = __builtin_amdgcn_mfma_f32_16x16x32_bf16(af, bf_, acc[nt], 0, 0, 0);
      }
    }
  }
#pragma unroll
  for (int nt = 0; nt < 4; ++nt) {
#pragma unroll
    for (int r = 0; r < 4; ++r) {
      int row = m0 + w * 16 + 4 * g + r;
      int col = n0 + nt * 16 + m16;
      float vv = acc[nt][r];
      if (EPI == 1) {
        float s = vv / (1.f + __expf(-vv));
        ((unsigned short*)Cp)[(size_t)row * N + col] = f2bf(s);
      } else {
        ((float*)Cp)[(size_t)row * N + col] = vv;
      }
    }
  }
}

// ---------------------------------------------------------------------------
// In-place RoPE over x[(b,t,heads,64)]: pair (i, i+32), i<32.
// ---------------------------------------------------------------------------
__global__ void rope_k(float* __restrict__ x, int nheads, int total) {
  int idx = blockIdx.x * 256 + threadIdx.x;
  if (idx >= total) return;
  int i = idx & 31;
  int rest = idx >> 5;
  int tpos = (rest / nheads) % NT;
  float* p = x + (size_t)rest * NDH;
  float ang = (float)tpos * powf(10000.0f, -(float)i * (1.0f / 32.0f));
  float sn, cs;
  sincosf(ang, &sn, &cs);
  float x1 = p[i], x2 = p[i + 32];
  p[i]      = x1 * cs - x2 * sn;
  p[i + 32] = x2 * cs + x1 * sn;
}

// ---------------------------------------------------------------------------
// MFMA flash attention v3: QBLK=128 (two q-halves per wave), KVBLK=64.
// Linear 72-u16 rows, split-b64 frag reads; SCALE folded into Q staging;
// work-balance blockIdx.x perm. Swapped-operand: S^T = mfma(K, Q);
// O^T = mfma(V^T, P^T). Per-lane scalar softmax state per half.
// ---------------------------------------------------------------------------
__device__ __forceinline__ bf8 frag64(const unsigned short* base, int row, int gr) {
  const unsigned short* rb = base + row * 72;
  us4 lo = *(const us4*)(rb + 4 * gr);
  us4 hi = *(const us4*)(rb + 4 * gr + 16);
  bf8 f;
  f[0] = (short)lo[0]; f[1] = (short)lo[1]; f[2] = (short)lo[2]; f[3] = (short)lo[3];
  f[4] = (short)hi[0]; f[5] = (short)hi[1]; f[6] = (short)hi[2]; f[7] = (short)hi[3];
  return f;
}
__device__ __forceinline__ bf8 frag64v(const unsigned short* base, int row, int gr) {
  const unsigned short* rb = base + row * 72 + 8 * ((row >> 3) & 1);
  us4 lo = *(const us4*)(rb + 4 * gr);
  us4 hi = *(const us4*)(rb + 4 * gr + 16);
  bf8 f;
  f[0] = (short)lo[0]; f[1] = (short)lo[1]; f[2] = (short)lo[2]; f[3] = (short)lo[3];
  f[4] = (short)hi[0]; f[5] = (short)hi[1]; f[6] = (short)hi[2]; f[7] = (short)hi[3];
  return f;
}

__global__ __launch_bounds__(256) void attn_mfma2_k(const float* __restrict__ qb,
                                                    const float* __restrict__ kb,
                                                    const float* __restrict__ vb,
                                                    const float* __restrict__ Wg,
                                                    const float* __restrict__ bg,
                                                    unsigned short* __restrict__ outp) {
  __shared__ __align__(16) char smem[45568];
  unsigned short* Qs  = (unsigned short*)smem;        // [128][72] 18432 B
  unsigned short* Ks  = Qs + 128 * 72;                //  9216 B
  unsigned short* Vt  = Ks + 64 * 72;                 //  9216 B (V^T rows=d)
  unsigned short* wgs = Vt + 64 * 72;                 //  8704 B [64][68] bf16
  float* outs = (float*)smem;                         // [128][68] f32 aliases Qs..Vt

  const int t = threadIdx.x;
  const int gx = gridDim.x;
  const int bx = blockIdx.x;
  const int bxp = (bx & 1) ? (gx - 1 - (bx >> 1)) : (bx >> 1);  // balance perm
  const int q0 = bxp * 128;
  const int bh = blockIdx.y;
  const int b = bh >> 4, h = bh & 15, kvh = h >> 2;
  const int lane = t & 63, wq = t >> 6;
  const int n = lane & 15, g = lane >> 4;
  const int srow = 4 * wq + g;
  const int c = n;

  // ---- stage Wgate (bf16) ----
#pragma unroll
  for (int i = 0; i < 4; ++i) {
    int id = t + 256 * i;                 // 0..1023 us4-chunks
    int row = id >> 4, cc = id & 15;
    fx4 wv = *(const fx4*)(Wg + (size_t)id * 4);
    us4 wb = { f2bf(wv[0]), f2bf(wv[1]), f2bf(wv[2]), f2bf(wv[3]) };
    *(us4*)(wgs + row * 68 + 4 * cc) = wb;
  }
  // ---- stage Q tile [128][64], scale folded (x0.125 exact) ----
#pragma unroll
  for (int i = 0; i < 8; ++i) {
    int id = t + 256 * i;                 // 0..2047 us4-chunks
    int row = id >> 4, cc = id & 15;
    fx4 a = *(const fx4*)(qb + (((size_t)b * NT + q0 + row) * NH + h) * NDH + 4 * cc);
    us4 ab = { f2bf(a[0] * 0.125f), f2bf(a[1] * 0.125f),
               f2bf(a[2] * 0.125f), f2bf(a[3] * 0.125f) };
    *(us4*)(Qs + row * 72 + 4 * cc) = ab;
  }
  __syncthreads();

  // ---- Q B-fragments for both halves ----
  const int qrow_l = wq * 16 + n;
  bf8 bq00 = frag64(Qs, qrow_l, g),      bq01 = frag64(Qs, qrow_l, g + 8);
  bf8 bq10 = frag64(Qs, 64 + qrow_l, g), bq11 = frag64(Qs, 64 + qrow_l, g + 8);

  float mrun0 = -INFINITY, lsum0 = 0.f, mrun1 = -INFINITY, lsum1 = 0.f;
  fx4 oacc0[4] = {{0.f,0.f,0.f,0.f},{0.f,0.f,0.f,0.f},{0.f,0.f,0.f,0.f},{0.f,0.f,0.f,0.f}};
  fx4 oacc1[4] = {{0.f,0.f,0.f,0.f},{0.f,0.f,0.f,0.f},{0.f,0.f,0.f,0.f},{0.f,0.f,0.f,0.f}};

  for (int s0 = 0; s0 <= q0 + 64; s0 += 64) {
    __syncthreads();
    // ---- stage K (linear) and V (in-register 4x4 transpose -> V^T) ----
#pragma unroll
    for (int i = 0; i < 4; ++i) {
      const int row = srow + 16 * i;
      const size_t base = (((size_t)b * NT + s0 + row) * NHKV + kvh) * NDH + 4 * c;
      fx4 kv4 = *(const fx4*)(kb + base);
      us4 ab = { f2bf(kv4[0]), f2bf(kv4[1]), f2bf(kv4[2]), f2bf(kv4[3]) };
      *(us4*)(Ks + row * 72 + 4 * c) = ab;

      fx4 vv4 = *(const fx4*)(vb + base);
      float u0 = vv4[0], u1 = vv4[1], u2 = vv4[2], u3 = vv4[3];
      float t0 = __shfl_xor((g & 2) ? u0 : u2, 32);
      float t1 = __shfl_xor((g & 2) ? u1 : u3, 32);
      if (g & 2) { u0 = t0; u1 = t1; } else { u2 = t0; u3 = t1; }
      float s0v = __shfl_xor((g & 1) ? u0 : u1, 16);
      float s1v = __shfl_xor((g & 1) ? u2 : u3, 16);
      if (g & 1) { u0 = s0v; u2 = s1v; } else { u1 = s0v; u3 = s1v; }
      const int dd = 4 * c + g;
      const int r0 = 4 * wq + 16 * i;
      us4 tv = { f2bf(u0), f2bf(u1), f2bf(u2), f2bf(u3) };
      *(us4*)(Vt + dd * 72 + 8 * ((dd >> 3) & 1) + r0) = tv;
    }
    __syncthreads();

    const int hstart = (s0 == q0 + 64) ? 1 : 0;
#pragma unroll
    for (int hh = 0; hh < 2; ++hh) {
      if (hh < hstart) continue;
      const bf8 bqa = hh ? bq10 : bq00;
      const bf8 bqb = hh ? bq11 : bq01;
      float sc[16];
#pragma unroll
      for (int nt = 0; nt < 4; ++nt) {
        const int krow = 16 * nt + n;
        bf8 ka0 = frag64(Ks, krow, g);
        bf8 ka1 = frag64(Ks, krow, g + 8);
        fx4 s4 = {0.f, 0.f, 0.f, 0.f};
        s4 = __builtin_amdgcn_mfma_f32_16x16x32_bf16(ka0, bqa, s4, 0, 0, 0);
        s4 = __builtin_amdgcn_mfma_f32_16x16x32_bf16(ka1, bqb, s4, 0, 0, 0);
#pragma unroll
        for (int r = 0; r < 4; ++r) sc[nt * 4 + r] = s4[r];
      }
      // diagonal mask: tile where keys align with this half's rows
      if (s0 == q0 + 64 * hh) {
#pragma unroll
        for (int nt = 0; nt < 4; ++nt)
#pragma unroll
          for (int r = 0; r < 4; ++r)
            if (16 * nt + 4 * g + r > qrow_l) sc[nt * 4 + r] = -INFINITY;
      }
      float mr = hh ? mrun1 : mrun0;
      float lz = hh ? lsum1 : lsum0;
      float tm = sc[0];
#pragma unroll
      for (int i = 1; i < 16; ++i) tm = fmaxf(tm, sc[i]);
      tm = fmaxf(tm, __shfl_xor(tm, 16));
      tm = fmaxf(tm, __shfl_xor(tm, 32));
      float mnew = fmaxf(mr, tm);
      float corr = __expf(mr - mnew);
      float p[16];
      float ls = 0.f;
#pragma unroll
      for (int i = 0; i < 16; ++i) { p[i] = __expf(sc[i] - mnew); ls += p[i]; }
      ls += __shfl_xor(ls, 16);
      ls += __shfl_xor(ls, 32);
      lz = lz * corr + ls;
      if (hh) { mrun1 = mnew; lsum1 = lz; } else { mrun0 = mnew; lsum0 = lz; }

      bf8 pb0, pb1;
#pragma unroll
      for (int j = 0; j < 8; ++j) {
        pb0[j] = (short)f2bf(p[j]);
        pb1[j] = (short)f2bf(p[8 + j]);
      }
#pragma unroll
      for (int dt = 0; dt < 4; ++dt) {
        const int vrow = 16 * dt + n;
        bf8 va0 = frag64v(Vt, vrow, g);
        bf8 va1 = frag64v(Vt, vrow, g + 8);
        if (hh) {
          oacc1[dt] *= corr;
          oacc1[dt] = __builtin_amdgcn_mfma_f32_16x16x32_bf16(va0, pb0, oacc1[dt], 0, 0, 0);
          oacc1[dt] = __builtin_amdgcn_mfma_f32_16x16x32_bf16(va1, pb1, oacc1[dt], 0, 0, 0);
        } else {
          oacc0[dt] *= corr;
          oacc0[dt] = __builtin_amdgcn_mfma_f32_16x16x32_bf16(va0, pb0, oacc0[dt], 0, 0, 0);
          oacc0[dt] = __builtin_amdgcn_mfma_f32_16x16x32_bf16(va1, pb1, oacc0[dt], 0, 0, 0);
        }
      }
    }
  }

  // ---- normalize and park O tiles in LDS (aliases dead Qs/Ks/Vt) ----
  __syncthreads();
  const float inv0 = 1.0f / lsum0, inv1 = 1.0f / lsum1;
#pragma unroll
  for (int dt = 0; dt < 4; ++dt)
#pragma unroll
    for (int r = 0; r < 4; ++r) {
      outs[(qrow_l) * 68 + 16 * dt + 4 * g + r]      = oacc0[dt][r] * inv0;
      outs[(64 + qrow_l) * 68 + 16 * dt + 4 * g + r] = oacc1[dt][r] * inv1;
    }
  __syncthreads();

  // ---- fused sigmoid gate epilogue (both halves) ----
  const int r = t >> 2, qd = t & 3;
#pragma unroll
  for (int ih = 0; ih < 2; ++ih) {
    const int rr = 64 * ih + r;
    fx4 gs[4];
#pragma unroll
    for (int j = 0; j < 4; ++j) gs[j] = *(const fx4*)(bg + qd * 16 + j * 4);
    for (int d = 0; d < 64; ++d) {
      float od = outs[rr * 68 + d];
      const unsigned short* wr = wgs + d * 68 + qd * 16;
#pragma unroll
      for (int j = 0; j < 4; ++j) {
        us4 wv = *(const us4*)(wr + j * 4);
        gs[j][0] += bf2f(wv[0]) * od;
        gs[j][1] += bf2f(wv[1]) * od;
        gs[j][2] += bf2f(wv[2]) * od;
        gs[j][3] += bf2f(wv[3]) * od;
      }
    }
    unsigned short* op = outp + ((size_t)b * NT + q0 + rr) * NDM + h * NDH + qd * 16;
#pragma unroll
    for (int j = 0; j < 4; ++j) {
      fx4 o = *(const fx4*)(outs + rr * 68 + qd * 16 + j * 4);
      us4 rbv;
#pragma unroll
      for (int e = 0; e < 4; ++e) {
        float gv = 1.f / (1.f + __expf(-gs[j][e]));
        rbv[e] = f2bf(o[e] * gv);
      }
      *(us4*)(op + j * 4) = rbv;
    }
  }
}

// ---------------------------------------------------------------------------
extern "C" void kernel_launch(void* const* d_in, const int* in_sizes, int n_in,
                              void* d_out, int out_size, void* d_ws, size_t ws_size,
                              hipStream_t stream) {
  const float* x    = (const float*)d_in[0];
  const float* Wq   = (const float*)d_in[1];
  const float* Wkvd = (const float*)d_in[2];
  const float* Wku  = (const float*)d_in[3];
  const float* Wvu  = (const float*)d_in[4];
  const float* Wg   = (const float*)d_in[5];
  const float* bg   = (const float*)d_in[6];
  const float* Wo1  = (const float*)d_in[7];
  const float* Wo2  = (const float*)d_in[8];
  float* out = (float*)d_out;
  char* ws = (char*)d_ws;

  // workspace layout (bytes); hbuf aliases q..xb (all dead before FFN1)
  float*          q     = (float*)(ws);                         // 16 MB f32
  float*          lat   = (float*)(ws + 16777216);              //  1 MB
  float*          kk    = (float*)(ws + 17825792);              //  4 MB
  float*          vv    = (float*)(ws + 22020096);              //  4 MB
  unsigned short* xb    = (unsigned short*)(ws + 26214400);     //  8 MB bf16
  unsigned short* hbuf  = (unsigned short*)(ws);                // 32 MB bf16 (alias)
  unsigned short* WqT   = (unsigned short*)(ws + 34602880);     //  2 MB bf16 [N,K]
  unsigned short* Wo1T  = (unsigned short*)(ws + 36700160);     //  8 MB bf16 [4096,1024]
  unsigned short* Wo2T  = (unsigned short*)(ws + 45088768);     //  8 MB bf16 [1024,4096]
  unsigned short* aob   = (unsigned short*)(ws + 53477376);     //  8 MB bf16

  const int MT = NB * NT;  // 4096 token rows
  dim3 blk(256);

  // bf16 pre-conversion (ws re-poisoned => every call)
  conv_bf_k<<<dim3(MT * NDM / 8 / 256), blk, 0, stream>>>(x, xb, MT * NDM / 8);
  convT_bf_k<<<dim3(NDM / 64, NDM / 64),  blk, 0, stream>>>(Wq,  WqT,  NDM, NDM);
  convT_bf_k<<<dim3(NDM / 64, NDFF / 64), blk, 0, stream>>>(Wo1, Wo1T, NDM, NDFF);
  convT_bf_k<<<dim3(NDFF / 64, NDM / 64), blk, 0, stream>>>(Wo2, Wo2T, NDFF, NDM);

  // projections
  gemm_bf_k<0><<<dim3(MT/128, NDM/128), blk, 0, stream>>>(xb, WqT, (void*)q, MT, NDM, NDM);
  gemm_k<0,0><<<dim3(MT/64, NLAT/64), blk, 0, stream>>>((const void*)x,   Wkvd, (void*)lat, MT, NLAT,      NDM);
  gemm_k<0,0><<<dim3(MT/64, (NHKV*NDH)/64), blk, 0, stream>>>((const void*)lat, Wku, (void*)kk, MT, NHKV*NDH, NLAT);
  gemm_k<0,0><<<dim3(MT/64, (NHKV*NDH)/64), blk, 0, stream>>>((const void*)lat, Wvu, (void*)vv, MT, NHKV*NDH, NLAT);

  int qpairs = NB * NT * NH * 32;
  int kpairs = NB * NT * NHKV * 32;
  rope_k<<<dim3((qpairs + 255) / 256), blk, 0, stream>>>(q,  NH,   qpairs);
  rope_k<<<dim3((kpairs + 255) / 256), blk, 0, stream>>>(kk, NHKV, kpairs);

  attn_mfma2_k<<<dim3(NT/128, NB*NH), blk, 0, stream>>>(q, kk, vv, Wg, bg, aob);

  // FFN
  gemm_bf_k<1><<<dim3(MT/128, NDFF/128), blk, 0, stream>>>(aob,  Wo1T, (void*)hbuf, MT, NDFF, NDM);
  gemm_bf_k<0><<<dim3(MT/128, NDM/128),  blk, 0, stream>>>(hbuf, Wo2T, (void*)out,  MT, NDM,  NDFF);
}